// Round 8
// baseline (529.051 us; speedup 1.0000x reference)
//
#include <hip/hip_runtime.h>
#include <hip/hip_bf16.h>

#define DI __device__ __forceinline__

DI float bfu(unsigned short u){ return __uint_as_float(((unsigned)u)<<16); }
DI unsigned short f2b(float f){            // fp32 -> bf16 RNE
  unsigned u = __float_as_uint(f);
  return (unsigned short)((u + 0x7FFFu + ((u >> 16) & 1u)) >> 16);
}

typedef __attribute__((ext_vector_type(8))) short short8;   // 8 bf16 = 4 VGPRs
typedef __attribute__((ext_vector_type(4))) float floatx4;  // MFMA acc

// weight offsets inside fp32 workspace copy
#define OFF_W1  0
#define OFF_AS1 65536
#define OFF_AD1 65664
#define OFF_B1  65792
#define OFF_W2  65920
#define OFF_AS2 67968
#define OFF_AD2 67984
#define OFF_B2  68000
#define W_TOTAL 68016

#define CW_BLOCKS ((W_TOTAL+255)/256)      // 266
#define W1B_BLOCKS 256

// ---------------- fused setup: dtype sniff + weight converts + counts init ----------
__global__ __launch_bounds__(256) void setup_k(const unsigned short* __restrict__ x,
    const void* W1, const void* as1, const void* ad1, const void* b1,
    const void* W2, const void* as2, const void* ad2, const void* b2,
    int* __restrict__ flagp, float* __restrict__ dst,
    unsigned short* __restrict__ W1b, int* __restrict__ counts, int N){
  int b = blockIdx.x;
  if(b < CW_BLOCKS + W1B_BLOCKS){
    __shared__ int cnt;
    if(threadIdx.x==0) cnt = 0;
    __syncthreads();
    unsigned short u = x[threadIdx.x];
    int e = (u >> 7) & 0xFF;
    if(e < 100 || e > 140) atomicAdd(&cnt, 1);
    __syncthreads();
    int flag = (cnt >= 8) ? 1 : 0;           // 1 = fp32, 0 = bf16
    if(b == 0 && threadIdx.x == 0) *flagp = flag;
    if(b < CW_BLOCKS){
      int i = b*256 + threadIdx.x;
      if(i < W_TOTAL){
        const void* src; int off;
        if(i < OFF_AS1){ src=W1;  off=i; }
        else if(i < OFF_AD1){ src=as1; off=i-OFF_AS1; }
        else if(i < OFF_B1 ){ src=ad1; off=i-OFF_AD1; }
        else if(i < OFF_W2 ){ src=b1;  off=i-OFF_B1; }
        else if(i < OFF_AS2){ src=W2;  off=i-OFF_W2; }
        else if(i < OFF_AD2){ src=as2; off=i-OFF_AS2; }
        else if(i < OFF_B2 ){ src=ad2; off=i-OFF_AD2; }
        else               { src=b2;  off=i-OFF_B2; }
        dst[i] = flag ? ((const float*)src)[off]
                      : bfu(((const unsigned short*)src)[off]);
      }
    } else {
      int j = (b - CW_BLOCKS)*256 + threadIdx.x;   // < 65536
      W1b[j] = flag ? f2b(((const float*)W1)[j]) : ((const unsigned short*)W1)[j];
    }
  } else {
    int i = (b - CW_BLOCKS - W1B_BLOCKS)*256 + threadIdx.x;
    if(i < N) counts[i] = 1;                 // self-loop pre-counted
  }
}

// ---------------- CSR build ----------------
// nt load: don't let the ei stream evict the atomic count lines from L2.
__global__ __launch_bounds__(256) void hist_k(const int* __restrict__ ei,
                                              int* __restrict__ counts, int E){
  int e = blockIdx.x*256 + threadIdx.x;
  if(e < E){
    int d = __builtin_nontemporal_load(ei + E + e);
    atomicAdd(&counts[d], 1);
  }
}

// -------- 3-phase parallel scan --------
__global__ __launch_bounds__(256) void bsum_k(const int* __restrict__ counts,
                                              int* __restrict__ bsum, int N){
  int i = blockIdx.x*256 + threadIdx.x;
  int v = (i < N) ? counts[i] : 0;
  #pragma unroll
  for(int o = 1; o < 64; o <<= 1) v += __shfl_xor(v, o);
  __shared__ int s[4];
  if((threadIdx.x & 63) == 0) s[threadIdx.x >> 6] = v;
  __syncthreads();
  if(threadIdx.x == 0) bsum[blockIdx.x] = s[0] + s[1] + s[2] + s[3];
}
__global__ __launch_bounds__(1024) void bscan_k(int* __restrict__ bsum, int nb){
  __shared__ int part[1024];
  int t = threadIdx.x;
  int v = (t < nb) ? bsum[t] : 0;
  part[t] = v;
  __syncthreads();
  for(int o = 1; o < 1024; o <<= 1){
    int u = (t >= o) ? part[t-o] : 0;
    __syncthreads();
    part[t] += u;
    __syncthreads();
  }
  if(t < nb) bsum[t] = part[t] - v;          // exclusive
}
__global__ __launch_bounds__(256) void csr_fill_k(const int* __restrict__ counts,
    const int* __restrict__ bsum, int* __restrict__ rowptr,
    int* __restrict__ cursor, int* __restrict__ csr_src, int N){
  __shared__ int part[256];
  int t = threadIdx.x;
  int i = blockIdx.x*256 + t;
  int c = (i < N) ? counts[i] : 0;
  part[t] = c;
  __syncthreads();
  for(int o = 1; o < 256; o <<= 1){
    int u = (t >= o) ? part[t-o] : 0;
    __syncthreads();
    part[t] += u;
    __syncthreads();
  }
  int excl = part[t] - c + bsum[blockIdx.x];
  if(i < N){
    rowptr[i] = excl;
    csr_src[excl] = i;                       // self-loop at slot 0 of row i
    cursor[i] = excl + 1;
    if(i == N-1) rowptr[N] = excl + c;
  }
}

// ---------------- XCD-range-partitioned scatter + nt edge reads ---------------------
// Round-0 fix: dst ranges pinned to XCDs via blockIdx%8 so csr_src lines fill in
// one L2. Round-7 counters showed WRITE still 66 MB (10x useful): the per-block
// ei stream (12.8 MB through a 4 MB L2) evicts partially-filled dirty csr_src
// lines. Round-8 fix: nontemporal ei loads -> stream bypasses/deprioritizes L2,
// dirty lines survive until full.
__global__ __launch_bounds__(256) void scatter_k(const int* __restrict__ ei,
    int* __restrict__ cursor, int* __restrict__ csr_src, int E, int N){
  int r  = blockIdx.x & 7;                   // dst range == XCD (round-robin)
  int nb = gridDim.x >> 3;                   // blocks per range
  int bi = blockIdx.x >> 3;                  // block index within range
  int R  = (N + 7) >> 3;
  int lo = r * R;
  int hi = lo + R; if(hi > N) hi = N;
  for(int e = bi*256 + (int)threadIdx.x; e < E; e += nb*256){
    int d = __builtin_nontemporal_load(ei + E + e);
    if(d >= lo && d < hi){
      int s = __builtin_nontemporal_load(ei + e);
      int pos = atomicAdd(&cursor[d], 1);
      csr_src[pos] = s;
    }
  }
}

// ---------------- layer 1 MFMA GEMM: h1 = x @ W1^T (bf16) + attention logits --------
// Round-7 counters: 76 us at 14% occupancy, 3% MfmaUtil -> grid-starved (391
// blocks = 6 waves/CU ceiling). Round-8: 16 rows/wave (was 32, tm loop dropped)
// -> 782 blocks, ~12 waves/CU, and acc VGPRs halve.
__global__ __launch_bounds__(256) void gemm1_mfma_k(const void* __restrict__ x,
    const int* __restrict__ flag, const unsigned short* __restrict__ W1b,
    const float* __restrict__ Wf, unsigned short* __restrict__ h1b,
    float* __restrict__ asrc1, float* __restrict__ adst1, int N){
  int wave = threadIdx.x >> 6, lane = threadIdx.x & 63;
  int q = lane >> 4, col = lane & 15;
  int nb = blockIdx.x*64 + wave*16;
  bool f32 = (*flag != 0);
  int cn0 = min(nb + col, N-1);

  floatx4 acc[8];
  #pragma unroll
  for(int t=0;t<8;++t) acc[t] = (floatx4){0.f,0.f,0.f,0.f};

  for(int ks=0; ks<16; ++ks){
    int k0 = ks*32 + q*8;
    short8 a0;
    if(f32){
      const float* x0 = (const float*)x + (size_t)cn0*512 + k0;
      union { short8 v; unsigned short u[8]; } A0;
      #pragma unroll
      for(int j=0;j<8;++j){ A0.u[j] = f2b(x0[j]); }
      a0 = A0.v;
    } else {
      a0 = *(const short8*)((const unsigned short*)x + (size_t)cn0*512 + k0);
    }
    #pragma unroll
    for(int t=0;t<8;++t){
      short8 b = *(const short8*)(W1b + ((size_t)(16*t + col))*512 + k0);
      acc[t] = __builtin_amdgcn_mfma_f32_16x16x32_bf16(a0, b, acc[t], 0,0,0);
    }
  }

  float asv[8], adv[8];
  #pragma unroll
  for(int t=0;t<8;++t){ asv[t] = Wf[OFF_AS1 + 16*t + col]; adv[t] = Wf[OFF_AD1 + 16*t + col]; }

  #pragma unroll
  for(int r=0;r<4;++r){
    int node = nb + q*4 + r;
    if(node >= N) continue;
    float vs = 0.f, vd = 0.f;
    #pragma unroll
    for(int t=0;t<8;++t){
      float v = acc[t][r];
      h1b[(size_t)node*128 + 16*t + col] = f2b(v);
      float ps = v*asv[t], pd = v*adv[t];
      #pragma unroll
      for(int o=1;o<16;o<<=1){ ps += __shfl_xor(ps,o); pd += __shfl_xor(pd,o); }
      if(col == t){ vs = ps; vd = pd; }
    }
    if(col < 8){
      asrc1[(size_t)node*8 + col] = vs;
      adst1[(size_t)node*8 + col] = vd;
    }
  }
}

// ---------------- layer 1 aggregate: exact round-3 structure (88.6 us proven) -------
// depth-3 rotation pipeline, single while(v0) exit — the only form hipcc compiles
// without spills (rounds 2/5/6 all spilled); pk_fma payload reverted (r7: -13 us
// regression). n0/nEnd: 2-launch split for rocprof top-5 visibility, perf-neutral.
__global__ __launch_bounds__(256) void agg1_k(const int* __restrict__ rowptr,
    const int* __restrict__ csr_src, const float* __restrict__ asrc1,
    const float* __restrict__ adst1, const unsigned short* __restrict__ h1b,
    const float* __restrict__ Wf,
    float* __restrict__ h2, float* __restrict__ asrc2, float* __restrict__ adst2,
    int n0, int nEnd){
  int n = n0 + blockIdx.x*4 + (threadIdx.x >> 6);
  int lane = threadIdx.x & 63;
  if(n >= nEnd) return;
  int g = lane >> 4;                 // edge group 0..3
  int cl = lane & 15;                // channel block: channels [8cl, 8cl+8)
  int h = cl >> 1;                   // head of this channel block
  float ad = adst1[n*8 + h];
  int end = rowptr[n+1];
  int p = rowptr[n] + g;

  float d = 0.f;
  float o[8];
  #pragma unroll
  for(int j=0;j<8;++j) o[j] = 0.f;

  union U { uint4 v; unsigned short u[8]; };
  const uint4 z4 = (uint4){0,0,0,0};

  bool v0 = p    < end;
  bool v1 = p+4  < end;
  bool v2 = p+8  < end;
  bool v3 = p+12 < end;
  int s0 = v0 ? csr_src[p]    : 0;
  int s1 = v1 ? csr_src[p+4]  : 0;
  int s2 = v2 ? csr_src[p+8]  : 0;
  float a0 = v0 ? asrc1[s0*8 + h] : 0.f;
  float a1 = v1 ? asrc1[s1*8 + h] : 0.f;
  U H0, H1, H2;
  H0.v = v0 ? *(const uint4*)(h1b + (size_t)s0*128 + 8*cl) : z4;
  H1.v = v1 ? *(const uint4*)(h1b + (size_t)s1*128 + 8*cl) : z4;

  while(v0){
    int s3 = v3 ? csr_src[p+12] : 0;            // csr, 3 ahead
    float a2 = v2 ? asrc1[s2*8 + h] : 0.f;      // gathers, 2 ahead
    H2.v = v2 ? *(const uint4*)(h1b + (size_t)s2*128 + 8*cl) : z4;
    float aa = a0 + ad;
    aa = aa > 0.f ? aa : 0.2f*aa;               // leaky_relu
    float w = __expf(aa);
    d += w;
    #pragma unroll
    for(int j=0;j<8;++j) o[j] = fmaf(w, bfu(H0.u[j]), o[j]);
    p += 4;
    v0 = v1; v1 = v2; v2 = v3; v3 = (p+12 < end);
    s2 = s3;
    a0 = a1; a1 = a2;
    H0.v = H1.v; H1.v = H2.v;
  }

  // merge the 4 group partial sums (plain adds)
  #pragma unroll
  for(int off = 16; off < 64; off <<= 1){
    d += __shfl_xor(d, off);
    #pragma unroll
    for(int j=0;j<8;++j) o[j] += __shfl_xor(o[j], off);
  }

  float inv = 1.f / (d + 1e-16f);
  float e[8];
  #pragma unroll
  for(int j=0;j<8;++j){
    float v = o[j]*inv + Wf[OFF_B1 + 8*cl + j];
    e[j] = v > 0.f ? v : (__expf(v) - 1.f);    // ELU (fast exp; |err|~1e-7)
  }
  // distributed W2 epilogue: group g computes classes 4g..4g+3
  float h2v = 0.f;
  #pragma unroll
  for(int c = 0; c < 4; ++c){
    int cls = 4*g + c;
    const float4* wr = (const float4*)(Wf + OFF_W2 + cls*128 + 8*cl);
    float4 w0 = wr[0], w1 = wr[1];
    float part = w0.x*e[0] + w0.y*e[1] + w0.z*e[2] + w0.w*e[3]
               + w1.x*e[4] + w1.y*e[5] + w1.z*e[6] + w1.w*e[7];
    part += __shfl_xor(part,1); part += __shfl_xor(part,2);
    part += __shfl_xor(part,4); part += __shfl_xor(part,8);
    if(cl == c) h2v = part;                  // lane (g, cl<4) holds class 4g+cl
  }
  if(cl < 4) h2[n*16 + 4*g + cl] = h2v;
  float ps = (cl < 4) ? h2v * Wf[OFF_AS2 + 4*g + cl] : 0.f;
  float pd = (cl < 4) ? h2v * Wf[OFF_AD2 + 4*g + cl] : 0.f;
  #pragma unroll
  for(int off = 1; off < 64; off <<= 1){ ps += __shfl_xor(ps,off); pd += __shfl_xor(pd,off); }
  if(lane == 0){ asrc2[n] = ps; adst2[n] = pd; }
}

// ---------------- layer 2 aggregate: round-3 structure (exact), log_softmax ---------
__global__ __launch_bounds__(256) void agg2_k(const int* __restrict__ rowptr,
    const int* __restrict__ csr_src, const float* __restrict__ asrc2,
    const float* __restrict__ adst2, const float* __restrict__ h2,
    const float* __restrict__ Wf, const int* __restrict__ flag,
    void* __restrict__ out, int N){
  int n = blockIdx.x*4 + (threadIdx.x >> 6);
  int lane = threadIdx.x & 63;
  if(n >= N) return;
  int g = lane >> 4, l = lane & 15;
  float ad = adst2[n];
  int end = rowptr[n+1];
  int p = rowptr[n] + g;

  float d = 0.f, o = 0.f;

  bool v0 = p    < end;
  bool v1 = p+4  < end;
  bool v2 = p+8  < end;
  bool v3 = p+12 < end;
  int s0 = v0 ? csr_src[p]    : 0;
  int s1 = v1 ? csr_src[p+4]  : 0;
  int s2 = v2 ? csr_src[p+8]  : 0;
  float a0 = v0 ? asrc2[s0] : 0.f;
  float a1 = v1 ? asrc2[s1] : 0.f;
  float h0 = v0 ? h2[s0*16 + l] : 0.f;
  float h1v = v1 ? h2[s1*16 + l] : 0.f;

  while(v0){
    int s3 = v3 ? csr_src[p+12] : 0;            // csr, 3 ahead
    float a2 = v2 ? asrc2[s2] : 0.f;            // gathers, 2 ahead
    float h2g = v2 ? h2[s2*16 + l] : 0.f;
    float aa = a0 + ad;
    aa = aa > 0.f ? aa : 0.2f*aa;
    float w = __expf(aa);
    d += w;
    o = fmaf(w, h0, o);
    p += 4;
    v0 = v1; v1 = v2; v2 = v3; v3 = (p+12 < end);
    s2 = s3;
    a0 = a1; a1 = a2;
    h0 = h1v; h1v = h2g;
  }

  #pragma unroll
  for(int off = 16; off < 64; off <<= 1){
    d += __shfl_xor(d, off);
    o += __shfl_xor(o, off);
  }

  float v = o/(d + 1e-16f) + Wf[OFF_B2 + l];
  float mx = v;
  #pragma unroll
  for(int off = 1; off < 16; off <<= 1) mx = fmaxf(mx, __shfl_xor(mx, off));
  float ex = __expf(v - mx), sum = ex;
  #pragma unroll
  for(int off = 1; off < 16; off <<= 1) sum += __shfl_xor(sum, off);
  float r = v - mx - __logf(sum);
  if(g == 0){
    if(*flag) ((float*)out)[(size_t)n*16 + l] = r;
    else      ((__hip_bfloat16*)out)[(size_t)n*16 + l] = __float2bfloat16(r);
  }
}

extern "C" void kernel_launch(void* const* d_in, const int* in_sizes, int n_in,
                              void* d_out, int out_size, void* d_ws, size_t ws_size,
                              hipStream_t stream){
  const void* x  = d_in[0];
  const int*  ei = (const int*)d_in[1];
  const int N  = in_sizes[0] / 512;
  const int E  = in_sizes[1] / 2;
  const int NB = (N + 255) / 256;            // scan blocks (196 for N=50000)

  // workspace layout
  int*   flag     = (int*)d_ws;
  float* Wf       = (float*)d_ws + 4;                    // W_TOTAL
  unsigned short* W1b = (unsigned short*)(Wf + W_TOTAL); // 65536 ushort
  unsigned short* h1b = W1b + 65536;                     // N*128 ushort
  float* asrc1    = (float*)(h1b + (size_t)N*128);       // N*8
  float* adst1    = asrc1 + (size_t)N*8;                 // N*8
  float* h2       = adst1 + (size_t)N*8;                 // N*16
  float* asrc2    = h2 + (size_t)N*16;                   // N
  float* adst2    = asrc2 + N;                           // N
  int*   rowptr   = (int*)(adst2 + N);                   // N+1
  int*   cursor   = rowptr + (N+1);                      // N (counts)
  int*   csr_src  = cursor + N;                          // E+N
  int*   bsum     = csr_src + (E+N);                     // NB

  int setup_blocks = CW_BLOCKS + W1B_BLOCKS + NB;
  hipLaunchKernelGGL(setup_k, dim3(setup_blocks), dim3(256), 0, stream,
                     (const unsigned short*)x,
                     d_in[2], d_in[3], d_in[4], d_in[5], d_in[6], d_in[7], d_in[8], d_in[9],
                     flag, Wf, W1b, cursor, N);
  hipLaunchKernelGGL(hist_k, dim3((E+255)/256), dim3(256), 0, stream, ei, cursor, E);
  hipLaunchKernelGGL(bsum_k, dim3(NB), dim3(256), 0, stream, cursor, bsum, N);
  hipLaunchKernelGGL(bscan_k, dim3(1), dim3(1024), 0, stream, bsum, NB);
  hipLaunchKernelGGL(csr_fill_k, dim3(NB), dim3(256), 0, stream,
                     cursor, bsum, rowptr, cursor, csr_src, N);
  hipLaunchKernelGGL(scatter_k, dim3(1024), dim3(256), 0, stream,
                     ei, cursor, csr_src, E, N);
  hipLaunchKernelGGL(gemm1_mfma_k, dim3((N+63)/64), dim3(256), 0, stream,
                     x, flag, W1b, Wf, h1b, asrc1, adst1, N);
  // agg1 split into two half-grid launches: perf-neutral (same code, disjoint node
  // ranges), keeps the #2..#3 kernels visible in the rocprof top-5.
  int half = (N + 1) / 2;
  hipLaunchKernelGGL(agg1_k, dim3((half+3)/4), dim3(256), 0, stream,
                     rowptr, csr_src, asrc1, adst1, h1b, Wf, h2, asrc2, adst2, 0, half);
  hipLaunchKernelGGL(agg1_k, dim3((N-half+3)/4), dim3(256), 0, stream,
                     rowptr, csr_src, asrc1, adst1, h1b, Wf, h2, asrc2, adst2, half, N);
  hipLaunchKernelGGL(agg2_k, dim3((N+3)/4), dim3(256), 0, stream,
                     rowptr, csr_src, asrc2, adst2, h2, Wf, flag, d_out, N);
}

// Round 10
// 494.995 us; speedup vs baseline: 1.0688x; 1.0688x over previous
//
#include <hip/hip_runtime.h>
#include <hip/hip_bf16.h>

#define DI __device__ __forceinline__

DI float bfu(unsigned short u){ return __uint_as_float(((unsigned)u)<<16); }
DI unsigned short f2b(float f){            // fp32 -> bf16 RNE
  unsigned u = __float_as_uint(f);
  return (unsigned short)((u + 0x7FFFu + ((u >> 16) & 1u)) >> 16);
}

typedef __attribute__((ext_vector_type(8))) short short8;   // 8 bf16 = 4 VGPRs
typedef __attribute__((ext_vector_type(4))) float floatx4;  // MFMA acc

// weight offsets inside fp32 workspace copy
#define OFF_W1  0
#define OFF_AS1 65536
#define OFF_AD1 65664
#define OFF_B1  65792
#define OFF_W2  65920
#define OFF_AS2 67968
#define OFF_AD2 67984
#define OFF_B2  68000
#define W_TOTAL 68016

#define CW_BLOCKS ((W_TOTAL+255)/256)      // 266
#define W1B_BLOCKS 256

// ---------------- fused setup: dtype sniff + weight converts + counts init ----------
__global__ __launch_bounds__(256) void setup_k(const unsigned short* __restrict__ x,
    const void* W1, const void* as1, const void* ad1, const void* b1,
    const void* W2, const void* as2, const void* ad2, const void* b2,
    int* __restrict__ flagp, float* __restrict__ dst,
    unsigned short* __restrict__ W1b, int* __restrict__ counts, int N){
  int b = blockIdx.x;
  if(b < CW_BLOCKS + W1B_BLOCKS){
    __shared__ int cnt;
    if(threadIdx.x==0) cnt = 0;
    __syncthreads();
    unsigned short u = x[threadIdx.x];
    int e = (u >> 7) & 0xFF;
    if(e < 100 || e > 140) atomicAdd(&cnt, 1);
    __syncthreads();
    int flag = (cnt >= 8) ? 1 : 0;           // 1 = fp32, 0 = bf16
    if(b == 0 && threadIdx.x == 0) *flagp = flag;
    if(b < CW_BLOCKS){
      int i = b*256 + threadIdx.x;
      if(i < W_TOTAL){
        const void* src; int off;
        if(i < OFF_AS1){ src=W1;  off=i; }
        else if(i < OFF_AD1){ src=as1; off=i-OFF_AS1; }
        else if(i < OFF_B1 ){ src=ad1; off=i-OFF_AD1; }
        else if(i < OFF_W2 ){ src=b1;  off=i-OFF_B1; }
        else if(i < OFF_AS2){ src=W2;  off=i-OFF_W2; }
        else if(i < OFF_AD2){ src=as2; off=i-OFF_AS2; }
        else if(i < OFF_B2 ){ src=ad2; off=i-OFF_AD2; }
        else               { src=b2;  off=i-OFF_B2; }
        dst[i] = flag ? ((const float*)src)[off]
                      : bfu(((const unsigned short*)src)[off]);
      }
    } else {
      int j = (b - CW_BLOCKS)*256 + threadIdx.x;   // < 65536
      W1b[j] = flag ? f2b(((const float*)W1)[j]) : ((const unsigned short*)W1)[j];
    }
  } else {
    int i = (b - CW_BLOCKS - W1B_BLOCKS)*256 + threadIdx.x;
    if(i < N) counts[i] = 1;                 // self-loop pre-counted
  }
}

// ---------------- CSR build ----------------
// nt load: don't let the ei stream evict the atomic count lines from L2.
__global__ __launch_bounds__(256) void hist_k(const int* __restrict__ ei,
                                              int* __restrict__ counts, int E){
  int e = blockIdx.x*256 + threadIdx.x;
  if(e < E){
    int d = __builtin_nontemporal_load(ei + E + e);
    atomicAdd(&counts[d], 1);
  }
}

// -------- 3-phase parallel scan --------
__global__ __launch_bounds__(256) void bsum_k(const int* __restrict__ counts,
                                              int* __restrict__ bsum, int N){
  int i = blockIdx.x*256 + threadIdx.x;
  int v = (i < N) ? counts[i] : 0;
  #pragma unroll
  for(int o = 1; o < 64; o <<= 1) v += __shfl_xor(v, o);
  __shared__ int s[4];
  if((threadIdx.x & 63) == 0) s[threadIdx.x >> 6] = v;
  __syncthreads();
  if(threadIdx.x == 0) bsum[blockIdx.x] = s[0] + s[1] + s[2] + s[3];
}
__global__ __launch_bounds__(1024) void bscan_k(int* __restrict__ bsum, int nb){
  __shared__ int part[1024];
  int t = threadIdx.x;
  int v = (t < nb) ? bsum[t] : 0;
  part[t] = v;
  __syncthreads();
  for(int o = 1; o < 1024; o <<= 1){
    int u = (t >= o) ? part[t-o] : 0;
    __syncthreads();
    part[t] += u;
    __syncthreads();
  }
  if(t < nb) bsum[t] = part[t] - v;          // exclusive
}
__global__ __launch_bounds__(256) void csr_fill_k(const int* __restrict__ counts,
    const int* __restrict__ bsum, int* __restrict__ rowptr,
    int* __restrict__ cursor, int* __restrict__ csr_src, int N){
  __shared__ int part[256];
  int t = threadIdx.x;
  int i = blockIdx.x*256 + t;
  int c = (i < N) ? counts[i] : 0;
  part[t] = c;
  __syncthreads();
  for(int o = 1; o < 256; o <<= 1){
    int u = (t >= o) ? part[t-o] : 0;
    __syncthreads();
    part[t] += u;
    __syncthreads();
  }
  int excl = part[t] - c + bsum[blockIdx.x];
  if(i < N){
    rowptr[i] = excl;
    csr_src[excl] = i;                       // self-loop at slot 0 of row i
    cursor[i] = excl + 1;
    if(i == N-1) rowptr[N] = excl + c;
  }
}

// ---------------- XCD-range-partitioned scatter + nt edge reads ---------------------
__global__ __launch_bounds__(256) void scatter_k(const int* __restrict__ ei,
    int* __restrict__ cursor, int* __restrict__ csr_src, int E, int N){
  int r  = blockIdx.x & 7;                   // dst range == XCD (round-robin)
  int nb = gridDim.x >> 3;                   // blocks per range
  int bi = blockIdx.x >> 3;                  // block index within range
  int R  = (N + 7) >> 3;
  int lo = r * R;
  int hi = lo + R; if(hi > N) hi = N;
  for(int e = bi*256 + (int)threadIdx.x; e < E; e += nb*256){
    int d = __builtin_nontemporal_load(ei + E + e);
    if(d >= lo && d < hi){
      int s = __builtin_nontemporal_load(ei + e);
      int pos = atomicAdd(&cursor[d], 1);
      csr_src[pos] = s;
    }
  }
}

// ---------------- layer 1 MFMA GEMM: h1 = x @ W1^T (bf16) + attention logits --------
// Round-8 lesson: latency-bound via ONE memory round trip per K-step; shrinking
// rows/wave doubled W1b traffic and regressed. Round-9: 32 rows/wave restored
// (best load:MFMA amortization) + K chunked by 64: all 20 loads (4 A + 16 B)
// issue per iteration, ONE wait, 32 MFMAs -> round trips/wave 16 -> 8.
// Straight-line unrolled body (no guarded CF -> no spill risk pattern).
__global__ __launch_bounds__(256) void gemm1_mfma_k(const void* __restrict__ x,
    const int* __restrict__ flag, const unsigned short* __restrict__ W1b,
    const float* __restrict__ Wf, unsigned short* __restrict__ h1b,
    float* __restrict__ asrc1, float* __restrict__ adst1, int N){
  int wave = threadIdx.x >> 6, lane = threadIdx.x & 63;
  int q = lane >> 4, col = lane & 15;
  int nb = blockIdx.x*128 + wave*32;
  bool f32 = (*flag != 0);
  int cn0 = min(nb + col, N-1);
  int cn1 = min(nb + 16 + col, N-1);

  floatx4 acc[2][8];
  #pragma unroll
  for(int tm=0;tm<2;++tm)
    #pragma unroll
    for(int t=0;t<8;++t) acc[tm][t] = (floatx4){0.f,0.f,0.f,0.f};

  const unsigned short* xb = (const unsigned short*)x;
  const float* xf = (const float*)x;

  for(int kc=0; kc<8; ++kc){                 // 64 K per chunk = 2 MFMA K-steps
    int k0 = kc*64 + q*8;
    short8 a00, a01, a10, a11;
    if(f32){
      union { short8 v; unsigned short u[8]; } A;
      const float* p00 = xf + (size_t)cn0*512 + k0;
      const float* p01 = p00 + 32;
      const float* p10 = xf + (size_t)cn1*512 + k0;
      const float* p11 = p10 + 32;
      #pragma unroll
      for(int j=0;j<8;++j) A.u[j] = f2b(p00[j]);  a00 = A.v;
      #pragma unroll
      for(int j=0;j<8;++j) A.u[j] = f2b(p01[j]);  a01 = A.v;
      #pragma unroll
      for(int j=0;j<8;++j) A.u[j] = f2b(p10[j]);  a10 = A.v;
      #pragma unroll
      for(int j=0;j<8;++j) A.u[j] = f2b(p11[j]);  a11 = A.v;
    } else {
      a00 = *(const short8*)(xb + (size_t)cn0*512 + k0);
      a01 = *(const short8*)(xb + (size_t)cn0*512 + k0 + 32);
      a10 = *(const short8*)(xb + (size_t)cn1*512 + k0);
      a11 = *(const short8*)(xb + (size_t)cn1*512 + k0 + 32);
    }
    short8 b0[8], b1[8];
    #pragma unroll
    for(int t=0;t<8;++t){
      const unsigned short* wrow = W1b + ((size_t)(16*t + col))*512 + k0;
      b0[t] = *(const short8*)(wrow);
      b1[t] = *(const short8*)(wrow + 32);
    }
    #pragma unroll
    for(int t=0;t<8;++t){
      acc[0][t] = __builtin_amdgcn_mfma_f32_16x16x32_bf16(a00, b0[t], acc[0][t], 0,0,0);
      acc[1][t] = __builtin_amdgcn_mfma_f32_16x16x32_bf16(a10, b0[t], acc[1][t], 0,0,0);
    }
    #pragma unroll
    for(int t=0;t<8;++t){
      acc[0][t] = __builtin_amdgcn_mfma_f32_16x16x32_bf16(a01, b1[t], acc[0][t], 0,0,0);
      acc[1][t] = __builtin_amdgcn_mfma_f32_16x16x32_bf16(a11, b1[t], acc[1][t], 0,0,0);
    }
  }

  float asv[8], adv[8];
  #pragma unroll
  for(int t=0;t<8;++t){ asv[t] = Wf[OFF_AS1 + 16*t + col]; adv[t] = Wf[OFF_AD1 + 16*t + col]; }

  #pragma unroll
  for(int tm=0;tm<2;++tm){
    #pragma unroll
    for(int r=0;r<4;++r){
      int node = nb + tm*16 + q*4 + r;
      if(node >= N) continue;
      float vs = 0.f, vd = 0.f;
      #pragma unroll
      for(int t=0;t<8;++t){
        float v = acc[tm][t][r];
        h1b[(size_t)node*128 + 16*t + col] = f2b(v);
        float ps = v*asv[t], pd = v*adv[t];
        #pragma unroll
        for(int o=1;o<16;o<<=1){ ps += __shfl_xor(ps,o); pd += __shfl_xor(pd,o); }
        if(col == t){ vs = ps; vd = pd; }
      }
      if(col < 8){
        asrc1[(size_t)node*8 + col] = vs;
        adst1[(size_t)node*8 + col] = vd;
      }
    }
  }
}

// ---------------- layer 1 aggregate: exact round-3 structure (88.6 us proven) -------
__global__ __launch_bounds__(256) void agg1_k(const int* __restrict__ rowptr,
    const int* __restrict__ csr_src, const float* __restrict__ asrc1,
    const float* __restrict__ adst1, const unsigned short* __restrict__ h1b,
    const float* __restrict__ Wf,
    float* __restrict__ h2, float* __restrict__ asrc2, float* __restrict__ adst2,
    int n0, int nEnd){
  int n = n0 + blockIdx.x*4 + (threadIdx.x >> 6);
  int lane = threadIdx.x & 63;
  if(n >= nEnd) return;
  int g = lane >> 4;                 // edge group 0..3
  int cl = lane & 15;                // channel block: channels [8cl, 8cl+8)
  int h = cl >> 1;                   // head of this channel block
  float ad = adst1[n*8 + h];
  int end = rowptr[n+1];
  int p = rowptr[n] + g;

  float d = 0.f;
  float o[8];
  #pragma unroll
  for(int j=0;j<8;++j) o[j] = 0.f;

  union U { uint4 v; unsigned short u[8]; };
  const uint4 z4 = (uint4){0,0,0,0};

  bool v0 = p    < end;
  bool v1 = p+4  < end;
  bool v2 = p+8  < end;
  bool v3 = p+12 < end;
  int s0 = v0 ? csr_src[p]    : 0;
  int s1 = v1 ? csr_src[p+4]  : 0;
  int s2 = v2 ? csr_src[p+8]  : 0;
  float a0 = v0 ? asrc1[s0*8 + h] : 0.f;
  float a1 = v1 ? asrc1[s1*8 + h] : 0.f;
  U H0, H1, H2;
  H0.v = v0 ? *(const uint4*)(h1b + (size_t)s0*128 + 8*cl) : z4;
  H1.v = v1 ? *(const uint4*)(h1b + (size_t)s1*128 + 8*cl) : z4;

  while(v0){
    int s3 = v3 ? csr_src[p+12] : 0;            // csr, 3 ahead
    float a2 = v2 ? asrc1[s2*8 + h] : 0.f;      // gathers, 2 ahead
    H2.v = v2 ? *(const uint4*)(h1b + (size_t)s2*128 + 8*cl) : z4;
    float aa = a0 + ad;
    aa = aa > 0.f ? aa : 0.2f*aa;               // leaky_relu
    float w = __expf(aa);
    d += w;
    #pragma unroll
    for(int j=0;j<8;++j) o[j] = fmaf(w, bfu(H0.u[j]), o[j]);
    p += 4;
    v0 = v1; v1 = v2; v2 = v3; v3 = (p+12 < end);
    s2 = s3;
    a0 = a1; a1 = a2;
    H0.v = H1.v; H1.v = H2.v;
  }

  // merge the 4 group partial sums (plain adds)
  #pragma unroll
  for(int off = 16; off < 64; off <<= 1){
    d += __shfl_xor(d, off);
    #pragma unroll
    for(int j=0;j<8;++j) o[j] += __shfl_xor(o[j], off);
  }

  float inv = 1.f / (d + 1e-16f);
  float e[8];
  #pragma unroll
  for(int j=0;j<8;++j){
    float v = o[j]*inv + Wf[OFF_B1 + 8*cl + j];
    e[j] = v > 0.f ? v : (__expf(v) - 1.f);    // ELU (fast exp; |err|~1e-7)
  }
  // distributed W2 epilogue: group g computes classes 4g..4g+3
  float h2v = 0.f;
  #pragma unroll
  for(int c = 0; c < 4; ++c){
    int cls = 4*g + c;
    const float4* wr = (const float4*)(Wf + OFF_W2 + cls*128 + 8*cl);
    float4 w0 = wr[0], w1 = wr[1];
    float part = w0.x*e[0] + w0.y*e[1] + w0.z*e[2] + w0.w*e[3]
               + w1.x*e[4] + w1.y*e[5] + w1.z*e[6] + w1.w*e[7];
    part += __shfl_xor(part,1); part += __shfl_xor(part,2);
    part += __shfl_xor(part,4); part += __shfl_xor(part,8);
    if(cl == c) h2v = part;                  // lane (g, cl<4) holds class 4g+cl
  }
  if(cl < 4) h2[n*16 + 4*g + cl] = h2v;
  float ps = (cl < 4) ? h2v * Wf[OFF_AS2 + 4*g + cl] : 0.f;
  float pd = (cl < 4) ? h2v * Wf[OFF_AD2 + 4*g + cl] : 0.f;
  #pragma unroll
  for(int off = 1; off < 64; off <<= 1){ ps += __shfl_xor(ps,off); pd += __shfl_xor(pd,off); }
  if(lane == 0){ asrc2[n] = ps; adst2[n] = pd; }
}

// ---------------- layer 2 aggregate: round-3 structure (exact), log_softmax ---------
__global__ __launch_bounds__(256) void agg2_k(const int* __restrict__ rowptr,
    const int* __restrict__ csr_src, const float* __restrict__ asrc2,
    const float* __restrict__ adst2, const float* __restrict__ h2,
    const float* __restrict__ Wf, const int* __restrict__ flag,
    void* __restrict__ out, int N){
  int n = blockIdx.x*4 + (threadIdx.x >> 6);
  int lane = threadIdx.x & 63;
  if(n >= N) return;
  int g = lane >> 4, l = lane & 15;
  float ad = adst2[n];
  int end = rowptr[n+1];
  int p = rowptr[n] + g;

  float d = 0.f, o = 0.f;

  bool v0 = p    < end;
  bool v1 = p+4  < end;
  bool v2 = p+8  < end;
  bool v3 = p+12 < end;
  int s0 = v0 ? csr_src[p]    : 0;
  int s1 = v1 ? csr_src[p+4]  : 0;
  int s2 = v2 ? csr_src[p+8]  : 0;
  float a0 = v0 ? asrc2[s0] : 0.f;
  float a1 = v1 ? asrc2[s1] : 0.f;
  float h0 = v0 ? h2[s0*16 + l] : 0.f;
  float h1v = v1 ? h2[s1*16 + l] : 0.f;

  while(v0){
    int s3 = v3 ? csr_src[p+12] : 0;            // csr, 3 ahead
    float a2 = v2 ? asrc2[s2] : 0.f;            // gathers, 2 ahead
    float h2g = v2 ? h2[s2*16 + l] : 0.f;
    float aa = a0 + ad;
    aa = aa > 0.f ? aa : 0.2f*aa;
    float w = __expf(aa);
    d += w;
    o = fmaf(w, h0, o);
    p += 4;
    v0 = v1; v1 = v2; v2 = v3; v3 = (p+12 < end);
    s2 = s3;
    a0 = a1; a1 = a2;
    h0 = h1v; h1v = h2g;
  }

  #pragma unroll
  for(int off = 16; off < 64; off <<= 1){
    d += __shfl_xor(d, off);
    o += __shfl_xor(o, off);
  }

  float v = o/(d + 1e-16f) + Wf[OFF_B2 + l];
  float mx = v;
  #pragma unroll
  for(int off = 1; off < 16; off <<= 1) mx = fmaxf(mx, __shfl_xor(mx, off));
  float ex = __expf(v - mx), sum = ex;
  #pragma unroll
  for(int off = 1; off < 16; off <<= 1) sum += __shfl_xor(sum, off);
  float r = v - mx - __logf(sum);
  if(g == 0){
    if(*flag) ((float*)out)[(size_t)n*16 + l] = r;
    else      ((__hip_bfloat16*)out)[(size_t)n*16 + l] = __float2bfloat16(r);
  }
}

extern "C" void kernel_launch(void* const* d_in, const int* in_sizes, int n_in,
                              void* d_out, int out_size, void* d_ws, size_t ws_size,
                              hipStream_t stream){
  const void* x  = d_in[0];
  const int*  ei = (const int*)d_in[1];
  const int N  = in_sizes[0] / 512;
  const int E  = in_sizes[1] / 2;
  const int NB = (N + 255) / 256;            // scan blocks (196 for N=50000)

  // workspace layout
  int*   flag     = (int*)d_ws;
  float* Wf       = (float*)d_ws + 4;                    // W_TOTAL
  unsigned short* W1b = (unsigned short*)(Wf + W_TOTAL); // 65536 ushort
  unsigned short* h1b = W1b + 65536;                     // N*128 ushort
  float* asrc1    = (float*)(h1b + (size_t)N*128);       // N*8
  float* adst1    = asrc1 + (size_t)N*8;                 // N*8
  float* h2       = adst1 + (size_t)N*8;                 // N*16
  float* asrc2    = h2 + (size_t)N*16;                   // N
  float* adst2    = asrc2 + N;                           // N
  int*   rowptr   = (int*)(adst2 + N);                   // N+1
  int*   cursor   = rowptr + (N+1);                      // N (counts)
  int*   csr_src  = cursor + N;                          // E+N
  int*   bsum     = csr_src + (E+N);                     // NB

  int setup_blocks = CW_BLOCKS + W1B_BLOCKS + NB;
  hipLaunchKernelGGL(setup_k, dim3(setup_blocks), dim3(256), 0, stream,
                     (const unsigned short*)x,
                     d_in[2], d_in[3], d_in[4], d_in[5], d_in[6], d_in[7], d_in[8], d_in[9],
                     flag, Wf, W1b, cursor, N);
  hipLaunchKernelGGL(hist_k, dim3((E+255)/256), dim3(256), 0, stream, ei, cursor, E);
  hipLaunchKernelGGL(bsum_k, dim3(NB), dim3(256), 0, stream, cursor, bsum, N);
  hipLaunchKernelGGL(bscan_k, dim3(1), dim3(1024), 0, stream, bsum, NB);
  hipLaunchKernelGGL(csr_fill_k, dim3(NB), dim3(256), 0, stream,
                     cursor, bsum, rowptr, cursor, csr_src, N);
  hipLaunchKernelGGL(scatter_k, dim3(1024), dim3(256), 0, stream,
                     ei, cursor, csr_src, E, N);
  hipLaunchKernelGGL(gemm1_mfma_k, dim3((N+127)/128), dim3(256), 0, stream,
                     x, flag, W1b, Wf, h1b, asrc1, adst1, N);
  // agg1 split into two half-grid launches: perf-neutral (same code, disjoint node
  // ranges), keeps the #2..#3 kernels visible in the rocprof top-5.
  int half = (N + 1) / 2;
  hipLaunchKernelGGL(agg1_k, dim3((half+3)/4), dim3(256), 0, stream,
                     rowptr, csr_src, asrc1, adst1, h1b, Wf, h2, asrc2, adst2, 0, half);
  hipLaunchKernelGGL(agg1_k, dim3((N-half+3)/4), dim3(256), 0, stream,
                     rowptr, csr_src, asrc1, adst1, h1b, Wf, h2, asrc2, adst2, half, N);
  hipLaunchKernelGGL(agg2_k, dim3((N+3)/4), dim3(256), 0, stream,
                     rowptr, csr_src, asrc2, adst2, h2, Wf, flag, d_out, N);
}

// Round 11
// 493.569 us; speedup vs baseline: 1.0719x; 1.0029x over previous
//
#include <hip/hip_runtime.h>
#include <hip/hip_bf16.h>

#define DI __device__ __forceinline__

DI float bfu(unsigned short u){ return __uint_as_float(((unsigned)u)<<16); }
DI unsigned short f2b(float f){            // fp32 -> bf16 RNE
  unsigned u = __float_as_uint(f);
  return (unsigned short)((u + 0x7FFFu + ((u >> 16) & 1u)) >> 16);
}

typedef __attribute__((ext_vector_type(8))) short short8;   // 8 bf16 = 4 VGPRs
typedef __attribute__((ext_vector_type(4))) float floatx4;  // MFMA acc

// weight offsets inside fp32 workspace copy
#define OFF_W1  0
#define OFF_AS1 65536
#define OFF_AD1 65664
#define OFF_B1  65792
#define OFF_W2  65920
#define OFF_AS2 67968
#define OFF_AD2 67984
#define OFF_B2  68000
#define W_TOTAL 68016

#define CW_BLOCKS ((W_TOTAL+255)/256)      // 266
#define W1B_BLOCKS 256

// ---------------- fused setup: dtype sniff + weight converts + counts init ----------
__global__ __launch_bounds__(256) void setup_k(const unsigned short* __restrict__ x,
    const void* W1, const void* as1, const void* ad1, const void* b1,
    const void* W2, const void* as2, const void* ad2, const void* b2,
    int* __restrict__ flagp, float* __restrict__ dst,
    unsigned short* __restrict__ W1b, int* __restrict__ counts, int N){
  int b = blockIdx.x;
  if(b < CW_BLOCKS + W1B_BLOCKS){
    __shared__ int cnt;
    if(threadIdx.x==0) cnt = 0;
    __syncthreads();
    unsigned short u = x[threadIdx.x];
    int e = (u >> 7) & 0xFF;
    if(e < 100 || e > 140) atomicAdd(&cnt, 1);
    __syncthreads();
    int flag = (cnt >= 8) ? 1 : 0;           // 1 = fp32, 0 = bf16
    if(b == 0 && threadIdx.x == 0) *flagp = flag;
    if(b < CW_BLOCKS){
      int i = b*256 + threadIdx.x;
      if(i < W_TOTAL){
        const void* src; int off;
        if(i < OFF_AS1){ src=W1;  off=i; }
        else if(i < OFF_AD1){ src=as1; off=i-OFF_AS1; }
        else if(i < OFF_B1 ){ src=ad1; off=i-OFF_AD1; }
        else if(i < OFF_W2 ){ src=b1;  off=i-OFF_B1; }
        else if(i < OFF_AS2){ src=W2;  off=i-OFF_W2; }
        else if(i < OFF_AD2){ src=as2; off=i-OFF_AS2; }
        else if(i < OFF_B2 ){ src=ad2; off=i-OFF_AD2; }
        else               { src=b2;  off=i-OFF_B2; }
        dst[i] = flag ? ((const float*)src)[off]
                      : bfu(((const unsigned short*)src)[off]);
      }
    } else {
      int j = (b - CW_BLOCKS)*256 + threadIdx.x;   // < 65536
      W1b[j] = flag ? f2b(((const float*)W1)[j]) : ((const unsigned short*)W1)[j];
    }
  } else {
    int i = (b - CW_BLOCKS - W1B_BLOCKS)*256 + threadIdx.x;
    if(i < N) counts[i] = 1;                 // self-loop pre-counted
  }
}

// ---------------- CSR build ----------------
__global__ __launch_bounds__(256) void hist_k(const int* __restrict__ ei,
                                              int* __restrict__ counts, int E){
  int e = blockIdx.x*256 + threadIdx.x;
  if(e < E) atomicAdd(&counts[ei[E+e]], 1);
}

// -------- 3-phase parallel scan --------
__global__ __launch_bounds__(256) void bsum_k(const int* __restrict__ counts,
                                              int* __restrict__ bsum, int N){
  int i = blockIdx.x*256 + threadIdx.x;
  int v = (i < N) ? counts[i] : 0;
  #pragma unroll
  for(int o = 1; o < 64; o <<= 1) v += __shfl_xor(v, o);
  __shared__ int s[4];
  if((threadIdx.x & 63) == 0) s[threadIdx.x >> 6] = v;
  __syncthreads();
  if(threadIdx.x == 0) bsum[blockIdx.x] = s[0] + s[1] + s[2] + s[3];
}
__global__ __launch_bounds__(1024) void bscan_k(int* __restrict__ bsum, int nb){
  __shared__ int part[1024];
  int t = threadIdx.x;
  int v = (t < nb) ? bsum[t] : 0;
  part[t] = v;
  __syncthreads();
  for(int o = 1; o < 1024; o <<= 1){
    int u = (t >= o) ? part[t-o] : 0;
    __syncthreads();
    part[t] += u;
    __syncthreads();
  }
  if(t < nb) bsum[t] = part[t] - v;          // exclusive
}
__global__ __launch_bounds__(256) void csr_fill_k(const int* __restrict__ counts,
    const int* __restrict__ bsum, int* __restrict__ rowptr,
    int* __restrict__ cursor, int* __restrict__ csr_src, int N){
  __shared__ int part[256];
  int t = threadIdx.x;
  int i = blockIdx.x*256 + t;
  int c = (i < N) ? counts[i] : 0;
  part[t] = c;
  __syncthreads();
  for(int o = 1; o < 256; o <<= 1){
    int u = (t >= o) ? part[t-o] : 0;
    __syncthreads();
    part[t] += u;
    __syncthreads();
  }
  int excl = part[t] - c + bsum[blockIdx.x];
  if(i < N){
    rowptr[i] = excl;
    csr_src[excl] = i;                       // self-loop at slot 0 of row i
    cursor[i] = excl + 1;
    if(i == N-1) rowptr[N] = excl + c;
  }
}

// ---------------- XCD-range-partitioned scatter (round-3 proven form) ----------------
// dst ranges pinned to XCDs via blockIdx%8 (L2-local csr_src fill). nt-load
// variant (r10) and int4 variant (r4) both neutral -> plain form kept. Remaining
// 78 us is the serialized per-edge atomic->store chain; not attacked further here.
__global__ __launch_bounds__(256) void scatter_k(const int* __restrict__ ei,
    int* __restrict__ cursor, int* __restrict__ csr_src, int E, int N){
  int r  = blockIdx.x & 7;                   // dst range == XCD (round-robin)
  int nb = gridDim.x >> 3;                   // blocks per range
  int bi = blockIdx.x >> 3;                  // block index within range
  int R  = (N + 7) >> 3;
  int lo = r * R;
  int hi = lo + R; if(hi > N) hi = N;
  for(int e = bi*256 + (int)threadIdx.x; e < E; e += nb*256){
    int d = ei[E + e];
    if(d >= lo && d < hi){
      int s = ei[e];
      int pos = atomicAdd(&cursor[d], 1);
      csr_src[pos] = s;
    }
  }
}

// ---------------- layer 1 MFMA GEMM: K chunked by 64 (r9: halves round trips) -------
__global__ __launch_bounds__(256) void gemm1_mfma_k(const void* __restrict__ x,
    const int* __restrict__ flag, const unsigned short* __restrict__ W1b,
    const float* __restrict__ Wf, unsigned short* __restrict__ h1b,
    float* __restrict__ asrc1, float* __restrict__ adst1, int N){
  int wave = threadIdx.x >> 6, lane = threadIdx.x & 63;
  int q = lane >> 4, col = lane & 15;
  int nb = blockIdx.x*128 + wave*32;
  bool f32 = (*flag != 0);
  int cn0 = min(nb + col, N-1);
  int cn1 = min(nb + 16 + col, N-1);

  floatx4 acc[2][8];
  #pragma unroll
  for(int tm=0;tm<2;++tm)
    #pragma unroll
    for(int t=0;t<8;++t) acc[tm][t] = (floatx4){0.f,0.f,0.f,0.f};

  const unsigned short* xb = (const unsigned short*)x;
  const float* xf = (const float*)x;

  for(int kc=0; kc<8; ++kc){                 // 64 K per chunk = 2 MFMA K-steps
    int k0 = kc*64 + q*8;
    short8 a00, a01, a10, a11;
    if(f32){
      union { short8 v; unsigned short u[8]; } A;
      const float* p00 = xf + (size_t)cn0*512 + k0;
      const float* p01 = p00 + 32;
      const float* p10 = xf + (size_t)cn1*512 + k0;
      const float* p11 = p10 + 32;
      #pragma unroll
      for(int j=0;j<8;++j) A.u[j] = f2b(p00[j]);  a00 = A.v;
      #pragma unroll
      for(int j=0;j<8;++j) A.u[j] = f2b(p01[j]);  a01 = A.v;
      #pragma unroll
      for(int j=0;j<8;++j) A.u[j] = f2b(p10[j]);  a10 = A.v;
      #pragma unroll
      for(int j=0;j<8;++j) A.u[j] = f2b(p11[j]);  a11 = A.v;
    } else {
      a00 = *(const short8*)(xb + (size_t)cn0*512 + k0);
      a01 = *(const short8*)(xb + (size_t)cn0*512 + k0 + 32);
      a10 = *(const short8*)(xb + (size_t)cn1*512 + k0);
      a11 = *(const short8*)(xb + (size_t)cn1*512 + k0 + 32);
    }
    short8 b0[8], b1[8];
    #pragma unroll
    for(int t=0;t<8;++t){
      const unsigned short* wrow = W1b + ((size_t)(16*t + col))*512 + k0;
      b0[t] = *(const short8*)(wrow);
      b1[t] = *(const short8*)(wrow + 32);
    }
    #pragma unroll
    for(int t=0;t<8;++t){
      acc[0][t] = __builtin_amdgcn_mfma_f32_16x16x32_bf16(a00, b0[t], acc[0][t], 0,0,0);
      acc[1][t] = __builtin_amdgcn_mfma_f32_16x16x32_bf16(a10, b0[t], acc[1][t], 0,0,0);
    }
    #pragma unroll
    for(int t=0;t<8;++t){
      acc[0][t] = __builtin_amdgcn_mfma_f32_16x16x32_bf16(a01, b1[t], acc[0][t], 0,0,0);
      acc[1][t] = __builtin_amdgcn_mfma_f32_16x16x32_bf16(a11, b1[t], acc[1][t], 0,0,0);
    }
  }

  float asv[8], adv[8];
  #pragma unroll
  for(int t=0;t<8;++t){ asv[t] = Wf[OFF_AS1 + 16*t + col]; adv[t] = Wf[OFF_AD1 + 16*t + col]; }

  #pragma unroll
  for(int tm=0;tm<2;++tm){
    #pragma unroll
    for(int r=0;r<4;++r){
      int node = nb + tm*16 + q*4 + r;
      if(node >= N) continue;
      float vs = 0.f, vd = 0.f;
      #pragma unroll
      for(int t=0;t<8;++t){
        float v = acc[tm][t][r];
        h1b[(size_t)node*128 + 16*t + col] = f2b(v);
        float ps = v*asv[t], pd = v*adv[t];
        #pragma unroll
        for(int o=1;o<16;o<<=1){ ps += __shfl_xor(ps,o); pd += __shfl_xor(pd,o); }
        if(col == t){ vs = ps; vd = pd; }
      }
      if(col < 8){
        asrc1[(size_t)node*8 + col] = vs;
        adst1[(size_t)node*8 + col] = vd;
      }
    }
  }
}

// ---------------- layer 1 aggregate: depth-4 pipeline (r3 form, +1 stage) ----------
// Same rotation + single while(v0) exit (only spill-free shape, r2/5/6). Gathers
// now issued 3 iters ahead (was 2), csr 4 ahead: ~3 gather-pairs in flight/wave
// (was 2) against the ~3.4 TB/s L3 gather path. +~6 VGPR.
__global__ __launch_bounds__(256) void agg1_k(const int* __restrict__ rowptr,
    const int* __restrict__ csr_src, const float* __restrict__ asrc1,
    const float* __restrict__ adst1, const unsigned short* __restrict__ h1b,
    const float* __restrict__ Wf,
    float* __restrict__ h2, float* __restrict__ asrc2, float* __restrict__ adst2,
    int n0, int nEnd){
  int n = n0 + blockIdx.x*4 + (threadIdx.x >> 6);
  int lane = threadIdx.x & 63;
  if(n >= nEnd) return;
  int g = lane >> 4;                 // edge group 0..3
  int cl = lane & 15;                // channel block: channels [8cl, 8cl+8)
  int h = cl >> 1;                   // head of this channel block
  float ad = adst1[n*8 + h];
  int end = rowptr[n+1];
  int p = rowptr[n] + g;

  float d = 0.f;
  float o[8];
  #pragma unroll
  for(int j=0;j<8;++j) o[j] = 0.f;

  union U { uint4 v; unsigned short u[8]; };
  const uint4 z4 = (uint4){0,0,0,0};

  bool v0 = p    < end;
  bool v1 = p+4  < end;
  bool v2 = p+8  < end;
  bool v3 = p+12 < end;
  bool v4 = p+16 < end;
  int s0 = v0 ? csr_src[p]    : 0;
  int s1 = v1 ? csr_src[p+4]  : 0;
  int s2 = v2 ? csr_src[p+8]  : 0;
  int s3 = v3 ? csr_src[p+12] : 0;
  float a0 = v0 ? asrc1[s0*8 + h] : 0.f;
  float a1 = v1 ? asrc1[s1*8 + h] : 0.f;
  float a2 = v2 ? asrc1[s2*8 + h] : 0.f;
  U H0, H1, H2, H3;
  H0.v = v0 ? *(const uint4*)(h1b + (size_t)s0*128 + 8*cl) : z4;
  H1.v = v1 ? *(const uint4*)(h1b + (size_t)s1*128 + 8*cl) : z4;
  H2.v = v2 ? *(const uint4*)(h1b + (size_t)s2*128 + 8*cl) : z4;

  while(v0){
    int s4 = v4 ? csr_src[p+16] : 0;            // csr, 4 ahead
    float a3 = v3 ? asrc1[s3*8 + h] : 0.f;      // gathers, 3 ahead
    H3.v = v3 ? *(const uint4*)(h1b + (size_t)s3*128 + 8*cl) : z4;
    float aa = a0 + ad;
    aa = aa > 0.f ? aa : 0.2f*aa;               // leaky_relu
    float w = __expf(aa);
    d += w;
    #pragma unroll
    for(int j=0;j<8;++j) o[j] = fmaf(w, bfu(H0.u[j]), o[j]);
    p += 4;
    v0 = v1; v1 = v2; v2 = v3; v3 = v4; v4 = (p+16 < end);
    s3 = s4;
    a0 = a1; a1 = a2; a2 = a3;
    H0.v = H1.v; H1.v = H2.v; H2.v = H3.v;
  }

  // merge the 4 group partial sums (plain adds)
  #pragma unroll
  for(int off = 16; off < 64; off <<= 1){
    d += __shfl_xor(d, off);
    #pragma unroll
    for(int j=0;j<8;++j) o[j] += __shfl_xor(o[j], off);
  }

  float inv = 1.f / (d + 1e-16f);
  float e[8];
  #pragma unroll
  for(int j=0;j<8;++j){
    float v = o[j]*inv + Wf[OFF_B1 + 8*cl + j];
    e[j] = v > 0.f ? v : (__expf(v) - 1.f);    // ELU (fast exp; |err|~1e-7)
  }
  // distributed W2 epilogue: group g computes classes 4g..4g+3
  float h2v = 0.f;
  #pragma unroll
  for(int c = 0; c < 4; ++c){
    int cls = 4*g + c;
    const float4* wr = (const float4*)(Wf + OFF_W2 + cls*128 + 8*cl);
    float4 w0 = wr[0], w1 = wr[1];
    float part = w0.x*e[0] + w0.y*e[1] + w0.z*e[2] + w0.w*e[3]
               + w1.x*e[4] + w1.y*e[5] + w1.z*e[6] + w1.w*e[7];
    part += __shfl_xor(part,1); part += __shfl_xor(part,2);
    part += __shfl_xor(part,4); part += __shfl_xor(part,8);
    if(cl == c) h2v = part;                  // lane (g, cl<4) holds class 4g+cl
  }
  if(cl < 4) h2[n*16 + 4*g + cl] = h2v;
  float ps = (cl < 4) ? h2v * Wf[OFF_AS2 + 4*g + cl] : 0.f;
  float pd = (cl < 4) ? h2v * Wf[OFF_AD2 + 4*g + cl] : 0.f;
  #pragma unroll
  for(int off = 1; off < 64; off <<= 1){ ps += __shfl_xor(ps,off); pd += __shfl_xor(pd,off); }
  if(lane == 0){ asrc2[n] = ps; adst2[n] = pd; }
}

// ---------------- layer 2 aggregate: depth-4 pipeline, log_softmax ------------------
__global__ __launch_bounds__(256) void agg2_k(const int* __restrict__ rowptr,
    const int* __restrict__ csr_src, const float* __restrict__ asrc2,
    const float* __restrict__ adst2, const float* __restrict__ h2,
    const float* __restrict__ Wf, const int* __restrict__ flag,
    void* __restrict__ out, int N){
  int n = blockIdx.x*4 + (threadIdx.x >> 6);
  int lane = threadIdx.x & 63;
  if(n >= N) return;
  int g = lane >> 4, l = lane & 15;
  float ad = adst2[n];
  int end = rowptr[n+1];
  int p = rowptr[n] + g;

  float d = 0.f, o = 0.f;

  bool v0 = p    < end;
  bool v1 = p+4  < end;
  bool v2 = p+8  < end;
  bool v3 = p+12 < end;
  bool v4 = p+16 < end;
  int s0 = v0 ? csr_src[p]    : 0;
  int s1 = v1 ? csr_src[p+4]  : 0;
  int s2 = v2 ? csr_src[p+8]  : 0;
  int s3 = v3 ? csr_src[p+12] : 0;
  float a0 = v0 ? asrc2[s0] : 0.f;
  float a1 = v1 ? asrc2[s1] : 0.f;
  float a2 = v2 ? asrc2[s2] : 0.f;
  float h0 = v0 ? h2[s0*16 + l] : 0.f;
  float h1v = v1 ? h2[s1*16 + l] : 0.f;
  float h2v = v2 ? h2[s2*16 + l] : 0.f;

  while(v0){
    int s4 = v4 ? csr_src[p+16] : 0;            // csr, 4 ahead
    float a3 = v3 ? asrc2[s3] : 0.f;            // gathers, 3 ahead
    float h3v = v3 ? h2[s3*16 + l] : 0.f;
    float aa = a0 + ad;
    aa = aa > 0.f ? aa : 0.2f*aa;
    float w = __expf(aa);
    d += w;
    o = fmaf(w, h0, o);
    p += 4;
    v0 = v1; v1 = v2; v2 = v3; v3 = v4; v4 = (p+16 < end);
    s3 = s4;
    a0 = a1; a1 = a2; a2 = a3;
    h0 = h1v; h1v = h2v; h2v = h3v;
  }

  #pragma unroll
  for(int off = 16; off < 64; off <<= 1){
    d += __shfl_xor(d, off);
    o += __shfl_xor(o, off);
  }

  float v = o/(d + 1e-16f) + Wf[OFF_B2 + l];
  float mx = v;
  #pragma unroll
  for(int off = 1; off < 16; off <<= 1) mx = fmaxf(mx, __shfl_xor(mx, off));
  float ex = __expf(v - mx), sum = ex;
  #pragma unroll
  for(int off = 1; off < 16; off <<= 1) sum += __shfl_xor(sum, off);
  float r = v - mx - __logf(sum);
  if(g == 0){
    if(*flag) ((float*)out)[(size_t)n*16 + l] = r;
    else      ((__hip_bfloat16*)out)[(size_t)n*16 + l] = __float2bfloat16(r);
  }
}

extern "C" void kernel_launch(void* const* d_in, const int* in_sizes, int n_in,
                              void* d_out, int out_size, void* d_ws, size_t ws_size,
                              hipStream_t stream){
  const void* x  = d_in[0];
  const int*  ei = (const int*)d_in[1];
  const int N  = in_sizes[0] / 512;
  const int E  = in_sizes[1] / 2;
  const int NB = (N + 255) / 256;            // scan blocks (196 for N=50000)

  // workspace layout
  int*   flag     = (int*)d_ws;
  float* Wf       = (float*)d_ws + 4;                    // W_TOTAL
  unsigned short* W1b = (unsigned short*)(Wf + W_TOTAL); // 65536 ushort
  unsigned short* h1b = W1b + 65536;                     // N*128 ushort
  float* asrc1    = (float*)(h1b + (size_t)N*128);       // N*8
  float* adst1    = asrc1 + (size_t)N*8;                 // N*8
  float* h2       = adst1 + (size_t)N*8;                 // N*16
  float* asrc2    = h2 + (size_t)N*16;                   // N
  float* adst2    = asrc2 + N;                           // N
  int*   rowptr   = (int*)(adst2 + N);                   // N+1
  int*   cursor   = rowptr + (N+1);                      // N (counts)
  int*   csr_src  = cursor + N;                          // E+N
  int*   bsum     = csr_src + (E+N);                     // NB

  int setup_blocks = CW_BLOCKS + W1B_BLOCKS + NB;
  hipLaunchKernelGGL(setup_k, dim3(setup_blocks), dim3(256), 0, stream,
                     (const unsigned short*)x,
                     d_in[2], d_in[3], d_in[4], d_in[5], d_in[6], d_in[7], d_in[8], d_in[9],
                     flag, Wf, W1b, cursor, N);
  hipLaunchKernelGGL(hist_k, dim3((E+255)/256), dim3(256), 0, stream, ei, cursor, E);
  hipLaunchKernelGGL(bsum_k, dim3(NB), dim3(256), 0, stream, cursor, bsum, N);
  hipLaunchKernelGGL(bscan_k, dim3(1), dim3(1024), 0, stream, bsum, NB);
  hipLaunchKernelGGL(csr_fill_k, dim3(NB), dim3(256), 0, stream,
                     cursor, bsum, rowptr, cursor, csr_src, N);
  hipLaunchKernelGGL(scatter_k, dim3(1024), dim3(256), 0, stream,
                     ei, cursor, csr_src, E, N);
  hipLaunchKernelGGL(gemm1_mfma_k, dim3((N+127)/128), dim3(256), 0, stream,
                     x, flag, W1b, Wf, h1b, asrc1, adst1, N);
  // agg1 split into two half-grid launches: perf-neutral (same code, disjoint node
  // ranges), keeps the #2..#3 kernels visible in the rocprof top-5.
  int half = (N + 1) / 2;
  hipLaunchKernelGGL(agg1_k, dim3((half+3)/4), dim3(256), 0, stream,
                     rowptr, csr_src, asrc1, adst1, h1b, Wf, h2, asrc2, adst2, 0, half);
  hipLaunchKernelGGL(agg1_k, dim3((N-half+3)/4), dim3(256), 0, stream,
                     rowptr, csr_src, asrc1, adst1, h1b, Wf, h2, asrc2, adst2, half, N);
  hipLaunchKernelGGL(agg2_k, dim3((N+3)/4), dim3(256), 0, stream,
                     rowptr, csr_src, asrc2, adst2, h2, Wf, flag, d_out, N);
}

// Round 13
// 483.734 us; speedup vs baseline: 1.0937x; 1.0203x over previous
//
#include <hip/hip_runtime.h>
#include <hip/hip_bf16.h>

#define DI __device__ __forceinline__

DI float bfu(unsigned short u){ return __uint_as_float(((unsigned)u)<<16); }
DI unsigned short f2b(float f){            // fp32 -> bf16 RNE
  unsigned u = __float_as_uint(f);
  return (unsigned short)((u + 0x7FFFu + ((u >> 16) & 1u)) >> 16);
}

typedef __attribute__((ext_vector_type(8))) short short8;   // 8 bf16 = 4 VGPRs
typedef __attribute__((ext_vector_type(4))) float floatx4;  // MFMA acc

// weight offsets inside fp32 workspace copy
#define OFF_W1  0
#define OFF_AS1 65536
#define OFF_AD1 65664
#define OFF_B1  65792
#define OFF_W2  65920
#define OFF_AS2 67968
#define OFF_AD2 67984
#define OFF_B2  68000
#define W_TOTAL 68016

#define CW_BLOCKS ((W_TOTAL+255)/256)      // 266
#define W1B_BLOCKS 256

// ---------------- fused setup: dtype sniff + weight converts + counts init ----------
__global__ __launch_bounds__(256) void setup_k(const unsigned short* __restrict__ x,
    const void* W1, const void* as1, const void* ad1, const void* b1,
    const void* W2, const void* as2, const void* ad2, const void* b2,
    int* __restrict__ flagp, float* __restrict__ dst,
    unsigned short* __restrict__ W1b, int* __restrict__ counts, int N){
  int b = blockIdx.x;
  if(b < CW_BLOCKS + W1B_BLOCKS){
    __shared__ int cnt;
    if(threadIdx.x==0) cnt = 0;
    __syncthreads();
    unsigned short u = x[threadIdx.x];
    int e = (u >> 7) & 0xFF;
    if(e < 100 || e > 140) atomicAdd(&cnt, 1);
    __syncthreads();
    int flag = (cnt >= 8) ? 1 : 0;           // 1 = fp32, 0 = bf16
    if(b == 0 && threadIdx.x == 0) *flagp = flag;
    if(b < CW_BLOCKS){
      int i = b*256 + threadIdx.x;
      if(i < W_TOTAL){
        const void* src; int off;
        if(i < OFF_AS1){ src=W1;  off=i; }
        else if(i < OFF_AD1){ src=as1; off=i-OFF_AS1; }
        else if(i < OFF_B1 ){ src=ad1; off=i-OFF_AD1; }
        else if(i < OFF_W2 ){ src=b1;  off=i-OFF_B1; }
        else if(i < OFF_AS2){ src=W2;  off=i-OFF_W2; }
        else if(i < OFF_AD2){ src=as2; off=i-OFF_AS2; }
        else if(i < OFF_B2 ){ src=ad2; off=i-OFF_AD2; }
        else               { src=b2;  off=i-OFF_B2; }
        dst[i] = flag ? ((const float*)src)[off]
                      : bfu(((const unsigned short*)src)[off]);
      }
    } else {
      int j = (b - CW_BLOCKS)*256 + threadIdx.x;   // < 65536
      W1b[j] = flag ? f2b(((const float*)W1)[j]) : ((const unsigned short*)W1)[j];
    }
  } else {
    int i = (b - CW_BLOCKS - W1B_BLOCKS)*256 + threadIdx.x;
    if(i < N) counts[i] = 1;                 // self-loop pre-counted
  }
}

// ---------------- CSR build ----------------
__global__ __launch_bounds__(256) void hist_k(const int* __restrict__ ei,
                                              int* __restrict__ counts, int E){
  int e = blockIdx.x*256 + threadIdx.x;
  if(e < E) atomicAdd(&counts[ei[E+e]], 1);
}

// -------- 3-phase parallel scan --------
__global__ __launch_bounds__(256) void bsum_k(const int* __restrict__ counts,
                                              int* __restrict__ bsum, int N){
  int i = blockIdx.x*256 + threadIdx.x;
  int v = (i < N) ? counts[i] : 0;
  #pragma unroll
  for(int o = 1; o < 64; o <<= 1) v += __shfl_xor(v, o);
  __shared__ int s[4];
  if((threadIdx.x & 63) == 0) s[threadIdx.x >> 6] = v;
  __syncthreads();
  if(threadIdx.x == 0) bsum[blockIdx.x] = s[0] + s[1] + s[2] + s[3];
}
__global__ __launch_bounds__(1024) void bscan_k(int* __restrict__ bsum, int nb){
  __shared__ int part[1024];
  int t = threadIdx.x;
  int v = (t < nb) ? bsum[t] : 0;
  part[t] = v;
  __syncthreads();
  for(int o = 1; o < 1024; o <<= 1){
    int u = (t >= o) ? part[t-o] : 0;
    __syncthreads();
    part[t] += u;
    __syncthreads();
  }
  if(t < nb) bsum[t] = part[t] - v;          // exclusive
}
__global__ __launch_bounds__(256) void csr_fill_k(const int* __restrict__ counts,
    const int* __restrict__ bsum, int* __restrict__ rowptr,
    int* __restrict__ cursor, int* __restrict__ csr_src, int N){
  __shared__ int part[256];
  int t = threadIdx.x;
  int i = blockIdx.x*256 + t;
  int c = (i < N) ? counts[i] : 0;
  part[t] = c;
  __syncthreads();
  for(int o = 1; o < 256; o <<= 1){
    int u = (t >= o) ? part[t-o] : 0;
    __syncthreads();
    part[t] += u;
    __syncthreads();
  }
  int excl = part[t] - c + bsum[blockIdx.x];
  if(i < N){
    rowptr[i] = excl;
    csr_src[excl] = i;                       // self-loop at slot 0 of row i
    cursor[i] = excl + 1;
    if(i == N-1) rowptr[N] = excl + c;
  }
}

// ---------------- XCD-range-partitioned scatter, depth-3 pipelined ------------------
// XCD partition (r0): dst ranges pinned via blockIdx%8 -> csr_src lines fill in one
// L2. r7/r10 counters: 77 us at 1.5 TB/s, VALU 3.8% -> latency-bound on the
// load->branch chain (next d-load can't issue until filter resolves). r12: depth-3
// rotation pipeline, d AND s loaded 2 iters ahead unconditionally (s-prefetch is
// L2-hit traffic on the 8x-replayed stream); single while(v0) exit (spill-safe
// shape per r2/5/6); filtered body = pure atomic + fire-and-forget store.
__global__ __launch_bounds__(256) void scatter_k(const int* __restrict__ ei,
    int* __restrict__ cursor, int* __restrict__ csr_src, int E, int N){
  int r  = blockIdx.x & 7;                   // dst range == XCD (round-robin)
  int nb = gridDim.x >> 3;                   // blocks per range
  int bi = blockIdx.x >> 3;                  // block index within range
  int R  = (N + 7) >> 3;
  int lo = r * R;
  int hi = lo + R; if(hi > N) hi = N;
  int stride = nb*256;
  int e0 = bi*256 + (int)threadIdx.x;

  bool v0 = e0 < E;
  bool v1 = e0 + stride < E;
  int d0 = v0 ? ei[E + e0] : 0;
  int s0 = v0 ? ei[e0]     : 0;
  int d1 = v1 ? ei[E + e0 + stride] : 0;
  int s1 = v1 ? ei[e0 + stride]     : 0;
  int e2 = e0 + 2*stride;

  while(v0){
    bool v2 = e2 < E;
    int d2 = v2 ? ei[E + e2] : 0;            // 2 iterations ahead
    int s2 = v2 ? ei[e2]     : 0;
    if(d0 >= lo && d0 < hi){
      int pos = atomicAdd(&cursor[d0], 1);
      csr_src[pos] = s0;
    }
    v0 = v1; v1 = v2;
    d0 = d1; d1 = d2;
    s0 = s1; s1 = s2;
    e2 += stride;
  }
}

// ---------------- layer 1 MFMA GEMM: h1 = x @ W1^T (bf16) + attention logits --------
// r3/r7 form (76.7 us). K-chunk-64 variant (r9-r11) measured neutral -> reverted.
__global__ __launch_bounds__(256) void gemm1_mfma_k(const void* __restrict__ x,
    const int* __restrict__ flag, const unsigned short* __restrict__ W1b,
    const float* __restrict__ Wf, unsigned short* __restrict__ h1b,
    float* __restrict__ asrc1, float* __restrict__ adst1, int N){
  int wave = threadIdx.x >> 6, lane = threadIdx.x & 63;
  int q = lane >> 4, col = lane & 15;
  int nb = blockIdx.x*128 + wave*32;
  bool f32 = (*flag != 0);
  int cn0 = min(nb + col, N-1);
  int cn1 = min(nb + 16 + col, N-1);

  floatx4 acc[2][8];
  #pragma unroll
  for(int tm=0;tm<2;++tm)
    #pragma unroll
    for(int t=0;t<8;++t) acc[tm][t] = (floatx4){0.f,0.f,0.f,0.f};

  for(int ks=0; ks<16; ++ks){
    int k0 = ks*32 + q*8;
    short8 a0, a1;
    if(f32){
      const float* x0 = (const float*)x + (size_t)cn0*512 + k0;
      const float* x1 = (const float*)x + (size_t)cn1*512 + k0;
      union { short8 v; unsigned short u[8]; } A0, A1;
      #pragma unroll
      for(int j=0;j<8;++j){ A0.u[j] = f2b(x0[j]); A1.u[j] = f2b(x1[j]); }
      a0 = A0.v; a1 = A1.v;
    } else {
      a0 = *(const short8*)((const unsigned short*)x + (size_t)cn0*512 + k0);
      a1 = *(const short8*)((const unsigned short*)x + (size_t)cn1*512 + k0);
    }
    #pragma unroll
    for(int t=0;t<8;++t){
      short8 b = *(const short8*)(W1b + ((size_t)(16*t + col))*512 + k0);
      acc[0][t] = __builtin_amdgcn_mfma_f32_16x16x32_bf16(a0, b, acc[0][t], 0,0,0);
      acc[1][t] = __builtin_amdgcn_mfma_f32_16x16x32_bf16(a1, b, acc[1][t], 0,0,0);
    }
  }

  float asv[8], adv[8];
  #pragma unroll
  for(int t=0;t<8;++t){ asv[t] = Wf[OFF_AS1 + 16*t + col]; adv[t] = Wf[OFF_AD1 + 16*t + col]; }

  #pragma unroll
  for(int tm=0;tm<2;++tm){
    #pragma unroll
    for(int r=0;r<4;++r){
      int node = nb + tm*16 + q*4 + r;
      if(node >= N) continue;
      float vs = 0.f, vd = 0.f;
      #pragma unroll
      for(int t=0;t<8;++t){
        float v = acc[tm][t][r];
        h1b[(size_t)node*128 + 16*t + col] = f2b(v);
        float ps = v*asv[t], pd = v*adv[t];
        #pragma unroll
        for(int o=1;o<16;o<<=1){ ps += __shfl_xor(ps,o); pd += __shfl_xor(pd,o); }
        if(col == t){ vs = ps; vd = pd; }
      }
      if(col < 8){
        asrc1[(size_t)node*8 + col] = vs;
        adst1[(size_t)node*8 + col] = vd;
      }
    }
  }
}

// ---------------- layer 1 aggregate: exact round-3 structure (88.6 us proven) -------
// depth-3 rotation pipeline, single while(v0) exit (only spill-free shape —
// r2/5/6 spilled). depth-4 (r11) and pk_fma (r7) both neutral/regressive ->
// reverted. Single launch (split cost ~8-10 us, r7/r10/r11 ledger).
__global__ __launch_bounds__(256) void agg1_k(const int* __restrict__ rowptr,
    const int* __restrict__ csr_src, const float* __restrict__ asrc1,
    const float* __restrict__ adst1, const unsigned short* __restrict__ h1b,
    const float* __restrict__ Wf,
    float* __restrict__ h2, float* __restrict__ asrc2, float* __restrict__ adst2, int N){
  int n = blockIdx.x*4 + (threadIdx.x >> 6);
  int lane = threadIdx.x & 63;
  if(n >= N) return;
  int g = lane >> 4;                 // edge group 0..3
  int cl = lane & 15;                // channel block: channels [8cl, 8cl+8)
  int h = cl >> 1;                   // head of this channel block
  float ad = adst1[n*8 + h];
  int end = rowptr[n+1];
  int p = rowptr[n] + g;

  float d = 0.f;
  float o[8];
  #pragma unroll
  for(int j=0;j<8;++j) o[j] = 0.f;

  union U { uint4 v; unsigned short u[8]; };
  const uint4 z4 = (uint4){0,0,0,0};

  bool v0 = p    < end;
  bool v1 = p+4  < end;
  bool v2 = p+8  < end;
  bool v3 = p+12 < end;
  int s0 = v0 ? csr_src[p]    : 0;
  int s1 = v1 ? csr_src[p+4]  : 0;
  int s2 = v2 ? csr_src[p+8]  : 0;
  float a0 = v0 ? asrc1[s0*8 + h] : 0.f;
  float a1 = v1 ? asrc1[s1*8 + h] : 0.f;
  U H0, H1, H2;
  H0.v = v0 ? *(const uint4*)(h1b + (size_t)s0*128 + 8*cl) : z4;
  H1.v = v1 ? *(const uint4*)(h1b + (size_t)s1*128 + 8*cl) : z4;

  while(v0){
    int s3 = v3 ? csr_src[p+12] : 0;            // csr, 3 ahead
    float a2 = v2 ? asrc1[s2*8 + h] : 0.f;      // gathers, 2 ahead
    H2.v = v2 ? *(const uint4*)(h1b + (size_t)s2*128 + 8*cl) : z4;
    float aa = a0 + ad;
    aa = aa > 0.f ? aa : 0.2f*aa;               // leaky_relu
    float w = __expf(aa);
    d += w;
    #pragma unroll
    for(int j=0;j<8;++j) o[j] = fmaf(w, bfu(H0.u[j]), o[j]);
    p += 4;
    v0 = v1; v1 = v2; v2 = v3; v3 = (p+12 < end);
    s2 = s3;
    a0 = a1; a1 = a2;
    H0.v = H1.v; H1.v = H2.v;
  }

  // merge the 4 group partial sums (plain adds)
  #pragma unroll
  for(int off = 16; off < 64; off <<= 1){
    d += __shfl_xor(d, off);
    #pragma unroll
    for(int j=0;j<8;++j) o[j] += __shfl_xor(o[j], off);
  }

  float inv = 1.f / (d + 1e-16f);
  float e[8];
  #pragma unroll
  for(int j=0;j<8;++j){
    float v = o[j]*inv + Wf[OFF_B1 + 8*cl + j];
    e[j] = v > 0.f ? v : (__expf(v) - 1.f);    // ELU (fast exp; |err|~1e-7)
  }
  // distributed W2 epilogue: group g computes classes 4g..4g+3
  float h2v = 0.f;
  #pragma unroll
  for(int c = 0; c < 4; ++c){
    int cls = 4*g + c;
    const float4* wr = (const float4*)(Wf + OFF_W2 + cls*128 + 8*cl);
    float4 w0 = wr[0], w1 = wr[1];
    float part = w0.x*e[0] + w0.y*e[1] + w0.z*e[2] + w0.w*e[3]
               + w1.x*e[4] + w1.y*e[5] + w1.z*e[6] + w1.w*e[7];
    part += __shfl_xor(part,1); part += __shfl_xor(part,2);
    part += __shfl_xor(part,4); part += __shfl_xor(part,8);
    if(cl == c) h2v = part;                  // lane (g, cl<4) holds class 4g+cl
  }
  if(cl < 4) h2[n*16 + 4*g + cl] = h2v;
  float ps = (cl < 4) ? h2v * Wf[OFF_AS2 + 4*g + cl] : 0.f;
  float pd = (cl < 4) ? h2v * Wf[OFF_AD2 + 4*g + cl] : 0.f;
  #pragma unroll
  for(int off = 1; off < 64; off <<= 1){ ps += __shfl_xor(ps,off); pd += __shfl_xor(pd,off); }
  if(lane == 0){ asrc2[n] = ps; adst2[n] = pd; }
}

// ---------------- layer 2 aggregate: round-3 structure (exact), log_softmax ---------
__global__ __launch_bounds__(256) void agg2_k(const int* __restrict__ rowptr,
    const int* __restrict__ csr_src, const float* __restrict__ asrc2,
    const float* __restrict__ adst2, const float* __restrict__ h2,
    const float* __restrict__ Wf, const int* __restrict__ flag,
    void* __restrict__ out, int N){
  int n = blockIdx.x*4 + (threadIdx.x >> 6);
  int lane = threadIdx.x & 63;
  if(n >= N) return;
  int g = lane >> 4, l = lane & 15;
  float ad = adst2[n];
  int end = rowptr[n+1];
  int p = rowptr[n] + g;

  float d = 0.f, o = 0.f;

  bool v0 = p    < end;
  bool v1 = p+4  < end;
  bool v2 = p+8  < end;
  bool v3 = p+12 < end;
  int s0 = v0 ? csr_src[p]    : 0;
  int s1 = v1 ? csr_src[p+4]  : 0;
  int s2 = v2 ? csr_src[p+8]  : 0;
  float a0 = v0 ? asrc2[s0] : 0.f;
  float a1 = v1 ? asrc2[s1] : 0.f;
  float h0 = v0 ? h2[s0*16 + l] : 0.f;
  float h1v = v1 ? h2[s1*16 + l] : 0.f;

  while(v0){
    int s3 = v3 ? csr_src[p+12] : 0;            // csr, 3 ahead
    float a2 = v2 ? asrc2[s2] : 0.f;            // gathers, 2 ahead
    float h2g = v2 ? h2[s2*16 + l] : 0.f;
    float aa = a0 + ad;
    aa = aa > 0.f ? aa : 0.2f*aa;
    float w = __expf(aa);
    d += w;
    o = fmaf(w, h0, o);
    p += 4;
    v0 = v1; v1 = v2; v2 = v3; v3 = (p+12 < end);
    s2 = s3;
    a0 = a1; a1 = a2;
    h0 = h1v; h1v = h2g;
  }

  #pragma unroll
  for(int off = 16; off < 64; off <<= 1){
    d += __shfl_xor(d, off);
    o += __shfl_xor(o, off);
  }

  float v = o/(d + 1e-16f) + Wf[OFF_B2 + l];
  float mx = v;
  #pragma unroll
  for(int off = 1; off < 16; off <<= 1) mx = fmaxf(mx, __shfl_xor(mx, off));
  float ex = __expf(v - mx), sum = ex;
  #pragma unroll
  for(int off = 1; off < 16; off <<= 1) sum += __shfl_xor(sum, off);
  float r = v - mx - __logf(sum);
  if(g == 0){
    if(*flag) ((float*)out)[(size_t)n*16 + l] = r;
    else      ((__hip_bfloat16*)out)[(size_t)n*16 + l] = __float2bfloat16(r);
  }
}

extern "C" void kernel_launch(void* const* d_in, const int* in_sizes, int n_in,
                              void* d_out, int out_size, void* d_ws, size_t ws_size,
                              hipStream_t stream){
  const void* x  = d_in[0];
  const int*  ei = (const int*)d_in[1];
  const int N  = in_sizes[0] / 512;
  const int E  = in_sizes[1] / 2;
  const int NB = (N + 255) / 256;            // scan blocks (196 for N=50000)

  // workspace layout
  int*   flag     = (int*)d_ws;
  float* Wf       = (float*)d_ws + 4;                    // W_TOTAL
  unsigned short* W1b = (unsigned short*)(Wf + W_TOTAL); // 65536 ushort
  unsigned short* h1b = W1b + 65536;                     // N*128 ushort
  float* asrc1    = (float*)(h1b + (size_t)N*128);       // N*8
  float* adst1    = asrc1 + (size_t)N*8;                 // N*8
  float* h2       = adst1 + (size_t)N*8;                 // N*16
  float* asrc2    = h2 + (size_t)N*16;                   // N
  float* adst2    = asrc2 + N;                           // N
  int*   rowptr   = (int*)(adst2 + N);                   // N+1
  int*   cursor   = rowptr + (N+1);                      // N (counts)
  int*   csr_src  = cursor + N;                          // E+N
  int*   bsum     = csr_src + (E+N);                     // NB

  int setup_blocks = CW_BLOCKS + W1B_BLOCKS + NB;
  hipLaunchKernelGGL(setup_k, dim3(setup_blocks), dim3(256), 0, stream,
                     (const unsigned short*)x,
                     d_in[2], d_in[3], d_in[4], d_in[5], d_in[6], d_in[7], d_in[8], d_in[9],
                     flag, Wf, W1b, cursor, N);
  hipLaunchKernelGGL(hist_k, dim3((E+255)/256), dim3(256), 0, stream, ei, cursor, E);
  hipLaunchKernelGGL(bsum_k, dim3(NB), dim3(256), 0, stream, cursor, bsum, N);
  hipLaunchKernelGGL(bscan_k, dim3(1), dim3(1024), 0, stream, bsum, NB);
  hipLaunchKernelGGL(csr_fill_k, dim3(NB), dim3(256), 0, stream,
                     cursor, bsum, rowptr, cursor, csr_src, N);
  hipLaunchKernelGGL(scatter_k, dim3(1024), dim3(256), 0, stream,
                     ei, cursor, csr_src, E, N);
  hipLaunchKernelGGL(gemm1_mfma_k, dim3((N+127)/128), dim3(256), 0, stream,
                     x, flag, W1b, Wf, h1b, asrc1, adst1, N);
  hipLaunchKernelGGL(agg1_k, dim3((N+3)/4), dim3(256), 0, stream,
                     rowptr, csr_src, asrc1, adst1, h1b, Wf, h2, asrc2, adst2, N);
  hipLaunchKernelGGL(agg2_k, dim3((N+3)/4), dim3(256), 0, stream,
                     rowptr, csr_src, asrc2, adst2, h2, Wf, flag, d_out, N);
}